// Round 6
// baseline (142725.610 us; speedup 1.0000x reference)
//
#include <hip/hip_runtime.h>

// ---------------- problem constants ----------------
#define D_HH   1024
#define DR1    512
#define DR2    256
#define RTOT   (DR1 + DR2)
#define TSTEPS 8192

// ---------------- fused scan config ----------------
#define NB     32          // WGs per layer (one XCD's 32 CUs, 1 WG/CU)
#define BS     1024        // threads per WG (16 waves)
#define HA     (D_HH / NB) // 32 h-rows per WG
#define QA     (RTOT / NB) // 24 reservoir rows per WG
#define NROWB  (HA + QA)   // 56 phase-B rows per WG
#define RING   64          // h1 ring depth (layer0 -> layer1), always L3
#define RMASK  (RING - 1)
#define NWG    256         // launched WGs; active: bid%8 in {0,1}
#define FASTCAP 2          // fast (sc0/L2) probes per escalation cycle

typedef __attribute__((ext_vector_type(2))) unsigned long long ull2;

__device__ __forceinline__ float dot4f(float4 a, float4 b) {
    return fmaf(a.x, b.x, fmaf(a.y, b.y, fmaf(a.z, b.z, a.w * b.w)));
}

// ---- tagged-value helpers: entry = (tag<<32)|f32bits -----------------------
__device__ __forceinline__ ull2 ld16f(const unsigned long long* p) {  // fast: local L2
    ull2 v;
    asm volatile("global_load_dwordx4 %0, %1, off sc0\n\ts_waitcnt vmcnt(0)"
                 : "=&v"(v) : "v"(p) : "memory");
    return v;
}
__device__ __forceinline__ ull2 ld16a(const unsigned long long* p) {  // authoritative: L3
    ull2 v;
    asm volatile("global_load_dwordx4 %0, %1, off sc0 sc1\n\ts_waitcnt vmcnt(0)"
                 : "=&v"(v) : "v"(p) : "memory");
    return v;
}
__device__ __forceinline__ unsigned long long ld8a(const unsigned long long* p) {
    unsigned long long v;
    asm volatile("global_load_dwordx2 %0, %1, off sc0 sc1\n\ts_waitcnt vmcnt(0)"
                 : "=&v"(v) : "v"(p) : "memory");
    return v;
}
// dual store: local-L2 visibility + L3 truth (same value, monotone tags)
__device__ __forceinline__ void st8dual(unsigned long long* p, int tag, unsigned pay) {
    unsigned long long pv = ((unsigned long long)(unsigned)tag << 32) | pay;
    asm volatile("global_store_dwordx2 %0, %1, off sc0\n\t"
                 "global_store_dwordx2 %0, %1, off sc0 sc1"
                 :: "v"(p), "v"(pv) : "memory");
}
__device__ __forceinline__ void st8g(unsigned long long* p, int tag, unsigned pay) {
    unsigned long long pv = ((unsigned long long)(unsigned)tag << 32) | pay;
    asm volatile("global_store_dwordx2 %0, %1, off sc0 sc1"
                 :: "v"(p), "v"(pv) : "memory");
}

// escalating poll of 2 adjacent entries: FASTCAP sc0 probes, then one sc0sc1
// probe (proven path), then sleep. Can NEVER hang: the authoritative probe is
// exactly R4's working read and producers always dual-store.
__device__ __forceinline__ float2 poll2e(const unsigned long long* p, int tgt) {
    for (;;) {
        for (int it = 0; it < FASTCAP; ++it) {
            ull2 v = ld16f(p);
            if ((int)(v[0] >> 32) >= tgt && (int)(v[1] >> 32) >= tgt)
                return make_float2(__uint_as_float((unsigned)v[0]),
                                   __uint_as_float((unsigned)v[1]));
        }
        ull2 v = ld16a(p);
        if ((int)(v[0] >> 32) >= tgt && (int)(v[1] >> 32) >= tgt)
            return make_float2(__uint_as_float((unsigned)v[0]),
                               __uint_as_float((unsigned)v[1]));
        __builtin_amdgcn_s_sleep(1);
    }
}
// authoritative-only poll (cross-XCD data: ring)
__device__ __forceinline__ float2 poll2a(const unsigned long long* p, int tgt) {
    for (;;) {
        ull2 v = ld16a(p);
        if ((int)(v[0] >> 32) >= tgt && (int)(v[1] >> 32) >= tgt)
            return make_float2(__uint_as_float((unsigned)v[0]),
                               __uint_as_float((unsigned)v[1]));
        __builtin_amdgcn_s_sleep(1);
    }
}

// Fused dual-layer persistent recurrent scan, one XCD per layer (heuristic
// placement; correctness independent of placement via escalating polls).
//   active WGs: lay = bid%8 (0/1), g = bid/8 (0..31); others exit.
//   h[i] of step t -> tag t+1 ; r[j] of step t -> tag t+1 (memset0 = init)
__global__ __launch_bounds__(BS, 4) void crsd_fused(
    const float* __restrict__ x,    // (T, D_HH) layer-0 input
    const float* __restrict__ Wx,   // (L, D_HH, D_HH)
    const float* __restrict__ Wh,   // (L, D_HH, D_HH)
    const float* __restrict__ bias, // (L, D_HH)
    const float* __restrict__ V1,   // (L, D_HH, DR1)
    const float* __restrict__ U1,   // (L, DR1, D_HH)
    const float* __restrict__ V2,   // (L, D_HH, DR2)
    const float* __restrict__ U2,   // (L, DR2, D_HH)
    float* __restrict__ out,        // (T, D_HH)
    unsigned long long* ring,       // RING*D_HH tagged h1 (L3)
    unsigned long long* h1s,        // D_HH tagged h (layer-0 peers)
    unsigned long long* h2s,        // D_HH tagged h (layer-1 peers)
    unsigned long long* r1s,        // RTOT tagged r (layer 0)
    unsigned long long* r2s,        // RTOT tagged r (layer 1)
    unsigned long long* prog)       // layer-1 progress (L3)
{
    const int bid = blockIdx.x;
    const int lay = bid & 7;
    if (lay > 1) return;
    const int g   = bid >> 3;       // 0..31
    const int tid = threadIdx.x;

    const float* wxp = Wx + (size_t)lay * D_HH * D_HH;
    const float* whp = Wh + (size_t)lay * D_HH * D_HH;
    const float* v1p = V1 + (size_t)lay * D_HH * DR1;
    const float* v2p = V2 + (size_t)lay * D_HH * DR2;
    const float* u1p = U1 + (size_t)lay * DR1 * D_HH;
    const float* u2p = U2 + (size_t)lay * DR2 * D_HH;
    const float* bp  = bias + (size_t)lay * D_HH;
    unsigned long long* rst  = lay ? r2s : r1s;
    unsigned long long* hloc = lay ? h2s : h1s;

    __shared__ __align__(16) float r_s[RTOT];
    __shared__ __align__(16) float h_s[D_HH];
    __shared__ __align__(16) float x_s[D_HH];
    __shared__ float zw[HA];

    // ---- phase A role: row rA (32 lanes/row, 32 rows); V rows in VGPRs ----
    const int rA = tid >> 5;        // 0..31
    const int p  = tid & 31;
    const int iA = g * HA + rA;
    float4 wa[6];
    {
        const float4* v1r = (const float4*)(v1p + (size_t)iA * DR1);
#pragma unroll
        for (int k = 0; k < 4; ++k) wa[k] = v1r[p + 32 * k];
        const float4* v2r = (const float4*)(v2p + (size_t)iA * DR2);
#pragma unroll
        for (int k = 0; k < 2; ++k) wa[4 + k] = v2r[p + 32 * k];
    }

    // ---- phase B role: row rB (16 lanes/row, 56 rows); Wh/U + Wx in VGPRs ----
    const int rB = tid >> 4;        // 0..63 (56 active)
    const int q  = tid & 15;
    const bool isZ = (rB < HA);
    const bool isQ = (rB >= HA) && (rB < NROWB);
    int jG = 0;
    float bi = 0.f;
    const float* brow = whp;
    const float* xrow = whp;
    if (isZ) {
        brow = whp + (size_t)(g * HA + rB) * D_HH;
        xrow = wxp + (size_t)(g * HA + rB) * D_HH;
        bi   = bp[g * HA + rB];
    } else if (isQ) {
        jG = g * QA + (rB - HA);
        brow = (jG < DR1) ? (u1p + (size_t)jG * D_HH)
                          : (u2p + (size_t)(jG - DR1) * D_HH);
    }
    float4 wb[16], wxr[16];
    {
        const float4* br = (const float4*)brow;
        const float4* xr = (const float4*)xrow;
#pragma unroll
        for (int k = 0; k < 16; ++k) { wb[k] = br[q + 16 * k]; wxr[k] = xr[q + 16 * k]; }
    }

    float rloc = 0.f;
    int   l2c  = 0;   // cached layer-1 progress (layer-0 tid0)

    // ---------------- prologue: x_0 and zw(t=0) ----------------
    if (lay == 0) {
        x_s[tid] = x[tid];
    } else if (tid < D_HH / 2) {
        float2 v = poll2a(&ring[2 * tid], 1);
        *(float2*)&x_s[2 * tid] = v;
    }
    __syncthreads();
    if (isZ) {
        const float4* x4 = (const float4*)x_s;
        float acc = 0.f;
#pragma unroll
        for (int k = 0; k < 16; ++k) acc += dot4f(wxr[k], x4[q + 16 * k]);
#pragma unroll
        for (int m = 8; m >= 1; m >>= 1) acc += __shfl_xor(acc, m);
        if (q == 0) zw[rB] = bi + acc;   // h_{-1}=0
    }

    // ---------------- main loop ----------------
    for (int t = 0; t < TSTEPS; ++t) {
        // layer-0 ring back-pressure (lazy; margin 4 slots vs RING=64)
        if (lay == 0 && tid == 0 && t - 60 > l2c) {
            for (;;) {
                unsigned long long v = ld8a(prog);
                if ((int)(v >> 32) >= t - 60) { l2c = (int)(v >> 32); break; }
                __builtin_amdgcn_s_sleep(1);
            }
        }

        // ---- stage r_{t-1}: 2 entries/thread, escalating ----
        if (tid < RTOT / 2) {
            float2 v = poll2e(&rst[2 * tid], t);
            *(float2*)&r_s[2 * tid] = v;
        }
        __syncthreads();

        // ---- phase A: h_t = tanh(zw + V1 r1 + V2 r2) ----
        {
            const float4* r1v = (const float4*)r_s;
            const float4* r2v = (const float4*)(r_s + DR1);
            float acc = dot4f(wa[0], r1v[p]);
            acc += dot4f(wa[1], r1v[p + 32]);
            acc += dot4f(wa[2], r1v[p + 64]);
            acc += dot4f(wa[3], r1v[p + 96]);
            acc += dot4f(wa[4], r2v[p]);
            acc += dot4f(wa[5], r2v[p + 32]);
#pragma unroll
            for (int m = 16; m >= 1; m >>= 1) acc += __shfl_xor(acc, m);
            if (p == 0) {
                float hv = tanhf(zw[rA] + acc);
                unsigned hb = __float_as_uint(hv);
                st8dual(&hloc[iA], t + 1, hb);   // peers: L2 fast + L3 truth
                if (lay == 0) {
                    st8g(&ring[(size_t)(t & RMASK) * D_HH + iA], t + 1, hb);
                } else {
                    out[(size_t)t * D_HH + iA] = hv;
                    if (iA == 0) st8g(prog, t + 1, 0u);
                }
                h_s[iA] = hv;                    // self-stage own rows
            }
        }

        // layer-0: prefetch x_{t+1} (off critical path)
        if (lay == 0) {
            const int ti = (t + 1 < TSTEPS) ? t + 1 : TSTEPS - 1;
            x_s[tid] = x[(size_t)ti * D_HH + tid];
        }

        // ---- stage h_t (skip own rows); layer-1 stages x_{t+1} first ----
        if (tid < D_HH / 2) {
            if (lay == 1 && t + 1 < TSTEPS) {
                float2 xv = poll2a(
                    &ring[(size_t)((t + 1) & RMASK) * D_HH + 2 * tid], t + 2);
                *(float2*)&x_s[2 * tid] = xv;
            }
            if ((tid >> 4) != g) {
                float2 hv = poll2e(&hloc[2 * tid], t + 1);
                *(float2*)&h_s[2 * tid] = hv;
            }
        }
        __syncthreads();

        // ---- phase B: Q rows -> r_t ; Z rows -> zw_{t+1} = b + Wx x_{t+1} + Wh h_t
        if (rB < NROWB) {
            const float4* h4 = (const float4*)h_s;
            float acc = 0.f;
#pragma unroll
            for (int k = 0; k < 16; ++k) acc += dot4f(wb[k], h4[q + 16 * k]);
            if (isZ) {
                const float4* x4 = (const float4*)x_s;
#pragma unroll
                for (int k = 0; k < 16; ++k) acc += dot4f(wxr[k], x4[q + 16 * k]);
            }
#pragma unroll
            for (int m = 8; m >= 1; m >>= 1) acc += __shfl_xor(acc, m);
            if (q == 0) {
                if (isZ) {
                    zw[rB] = bi + acc;
                } else {
                    rloc = 0.9f * rloc + 0.1f * tanhf(acc);
                    st8dual(&rst[jG], t + 1, __float_as_uint(rloc));
                }
            }
        }
    }
}

extern "C" void kernel_launch(void* const* d_in, const int* in_sizes, int n_in,
                              void* d_out, int out_size, void* d_ws, size_t ws_size,
                              hipStream_t stream)
{
    const float* x  = (const float*)d_in[0];
    const float* Wx = (const float*)d_in[1];
    const float* Wh = (const float*)d_in[2];
    const float* b  = (const float*)d_in[3];
    const float* V1 = (const float*)d_in[4];
    const float* U1 = (const float*)d_in[5];
    const float* V2 = (const float*)d_in[6];
    const float* U2 = (const float*)d_in[7];
    float* out = (float*)d_out;

    unsigned long long* ring = (unsigned long long*)d_ws;          // RING*D_HH
    unsigned long long* h1s  = ring + (size_t)RING * D_HH;         // D_HH
    unsigned long long* h2s  = h1s + D_HH;                         // D_HH
    unsigned long long* r1s  = h2s + D_HH;                         // RTOT
    unsigned long long* r2s  = r1s + RTOT;                         // RTOT
    unsigned long long* prog = r2s + RTOT;                         // 8 (pad)
    const size_t stateB =
        ((size_t)RING * D_HH + 2 * D_HH + 2 * RTOT + 8) * sizeof(unsigned long long);

    hipMemsetAsync(d_ws, 0, stateB, stream);
    crsd_fused<<<dim3(NWG), dim3(BS), 0, stream>>>(
        x, Wx, Wh, b, V1, U1, V2, U2, out,
        ring, h1s, h2s, r1s, r2s, prog);
}

// Round 7
// 33740.570 us; speedup vs baseline: 4.2301x; 4.2301x over previous
//
#include <hip/hip_runtime.h>

// ---------------- problem constants ----------------
#define D_HH   1024
#define DR1    512
#define DR2    256
#define RTOT   (DR1 + DR2)
#define TSTEPS 8192

// ---------------- fused scan config (R4-proven shape) ----------------
#define NB     64          // WGs per layer (2 layers -> 128 WGs)
#define BS     512         // threads per WG (8 waves)
#define HA     (D_HH / NB) // 16 h-rows per WG
#define QA     (RTOT / NB) // 12 reservoir rows per WG
#define NROWB  (HA + QA)   // 28 phase-B rows per WG
#define RING   64          // h1 ring depth (layer0 -> layer1)
#define RMASK  (RING - 1)
#define NREP   4           // broadcast replicas for h/r state

typedef __attribute__((ext_vector_type(2))) unsigned long long ull2;

__device__ __forceinline__ float dot4f(float4 a, float4 b) {
    return fmaf(a.x, b.x, fmaf(a.y, b.y, fmaf(a.z, b.z, a.w * b.w)));
}

// ---- tagged-value helpers: entry = (tag<<32)|f32bits; all ops sc0+sc1 (L3
// truth — the R4/R6-proven visibility path). No sc0-only ops (refuted in R6).
__device__ __forceinline__ ull2 ld16(const unsigned long long* p) {
    ull2 v;
    asm volatile("global_load_dwordx4 %0, %1, off sc0 sc1\n\ts_waitcnt vmcnt(0)"
                 : "=&v"(v) : "v"(p) : "memory");
    return v;
}
__device__ __forceinline__ void ld16x2(const unsigned long long* p0,
                                       const unsigned long long* p1,
                                       ull2& a, ull2& b) {
    asm volatile("global_load_dwordx4 %0, %2, off sc0 sc1\n\t"
                 "global_load_dwordx4 %1, %3, off sc0 sc1\n\t"
                 "s_waitcnt vmcnt(0)"
                 : "=&v"(a), "=&v"(b) : "v"(p0), "v"(p1) : "memory");
}
__device__ __forceinline__ unsigned long long ld8(const unsigned long long* p) {
    unsigned long long v;
    asm volatile("global_load_dwordx2 %0, %1, off sc0 sc1\n\ts_waitcnt vmcnt(0)"
                 : "=&v"(v) : "v"(p) : "memory");
    return v;
}
__device__ __forceinline__ void st16(unsigned long long* p,
                                     unsigned long long lo, unsigned long long hi) {
    ull2 pv; pv[0] = lo; pv[1] = hi;
    asm volatile("global_store_dwordx4 %0, %1, off sc0 sc1"
                 :: "v"(p), "v"(pv) : "memory");
}
__device__ __forceinline__ void st8(unsigned long long* p, int tag, unsigned pay) {
    unsigned long long pv = ((unsigned long long)(unsigned)tag << 32) | pay;
    asm volatile("global_store_dwordx2 %0, %1, off sc0 sc1"
                 :: "v"(p), "v"(pv) : "memory");
}
__device__ __forceinline__ unsigned long long mktag(int tag, float v) {
    return ((unsigned long long)(unsigned)tag << 32) | __float_as_uint(v);
}

// Fused dual-layer persistent recurrent scan (R4 protocol + NREP replicated
// broadcast + paired 16B publication).
//   blocks 0..63 = layer 0 (x from global, h1 -> tagged ring)
//   blocks 64..127 = layer 1 (x = h1 from ring, writes out)
//   h[i] of step t -> tag t+1 ; r[j] of step t -> tag t+1 (memset0 = init)
__global__ __launch_bounds__(BS, 2) void crsd_fused(
    const float* __restrict__ x,    // (T, D_HH)
    const float* __restrict__ Wx,   // (L, D_HH, D_HH)
    const float* __restrict__ Wh,   // (L, D_HH, D_HH)
    const float* __restrict__ bias, // (L, D_HH)
    const float* __restrict__ V1,   // (L, D_HH, DR1)
    const float* __restrict__ U1,   // (L, DR1, D_HH)
    const float* __restrict__ V2,   // (L, D_HH, DR2)
    const float* __restrict__ U2,   // (L, DR2, D_HH)
    float* __restrict__ out,        // (T, D_HH)
    unsigned long long* ring,       // RING*D_HH tagged h1 (single copy)
    unsigned long long* h1rep,      // NREP*D_HH tagged h (layer 0)
    unsigned long long* h2rep,      // NREP*D_HH tagged h (layer 1)
    unsigned long long* r1rep,      // NREP*RTOT tagged r (layer 0)
    unsigned long long* r2rep,      // NREP*RTOT tagged r (layer 1)
    unsigned long long* prog)       // layer-1 progress cell
{
    const int gid = blockIdx.x;
    const int lay = gid >> 6;
    const int g   = gid & (NB - 1);
    const int tid = threadIdx.x;

    const float* wxp = Wx + (size_t)lay * D_HH * D_HH;
    const float* whp = Wh + (size_t)lay * D_HH * D_HH;
    const float* v1p = V1 + (size_t)lay * D_HH * DR1;
    const float* v2p = V2 + (size_t)lay * D_HH * DR2;
    const float* u1p = U1 + (size_t)lay * DR1 * D_HH;
    const float* u2p = U2 + (size_t)lay * DR2 * D_HH;
    const float* bp  = bias + (size_t)lay * D_HH;
    unsigned long long* rrep = lay ? r2rep : r1rep;
    unsigned long long* hrep = lay ? h2rep : h1rep;
    const int rep = g & (NREP - 1);     // which replica this WG polls

    __shared__ __align__(16) float r_s[RTOT];
    __shared__ __align__(16) float h_s[D_HH];
    __shared__ __align__(16) float x_s[D_HH];
    __shared__ float zw[HA];

    // ---- phase A role: row rA (32 lanes/row); V rows in VGPRs (permuted) ----
    const int rA = tid >> 5;
    const int p  = tid & 31;
    const int iA = g * HA + rA;
    float4 wa[6];
    {
        const float4* v1r = (const float4*)(v1p + (size_t)iA * DR1);
#pragma unroll
        for (int k = 0; k < 4; ++k) wa[k] = v1r[p + 32 * k];
        const float4* v2r = (const float4*)(v2p + (size_t)iA * DR2);
#pragma unroll
        for (int k = 0; k < 2; ++k) wa[4 + k] = v2r[p + 32 * k];
    }

    // ---- phase B role: row rB (16 lanes/row); Wh/U + Wx rows in VGPRs ----
    const int rB = tid >> 4;
    const int q  = tid & 15;
    const bool isZ = (rB < HA);
    const bool isQ = (rB >= HA) && (rB < NROWB);
    int jG = 0;
    float bi = 0.f;
    const float* brow = whp;
    const float* xrow = whp;
    if (isZ) {
        brow = whp + (size_t)(g * HA + rB) * D_HH;
        xrow = wxp + (size_t)(g * HA + rB) * D_HH;
        bi   = bp[g * HA + rB];
    } else if (isQ) {
        jG = g * QA + (rB - HA);
        brow = (jG < DR1) ? (u1p + (size_t)jG * D_HH)
                          : (u2p + (size_t)(jG - DR1) * D_HH);
    }
    float4 wb[16], wxr[16];
    {
        const float4* br = (const float4*)brow;
        const float4* xr = (const float4*)xrow;
#pragma unroll
        for (int k = 0; k < 16; ++k) { wb[k] = br[q + 16 * k]; wxr[k] = xr[q + 16 * k]; }
    }

    float rloc0 = 0.f, rloc1 = 0.f;  // even-Q-row lane 0 owns entries jG, jG+1
    int   l2c   = 0;                 // cached layer-1 progress (layer-0 tid0)

    // ---------------- prologue: x_0 and zw(t=0) ----------------
    if (lay == 0) {
        float2 xv = *(const float2*)&x[2 * tid];
        *(float2*)&x_s[2 * tid] = xv;
    } else {
        const unsigned long long* px0 = &ring[2 * tid];
        for (;;) {
            ull2 v = ld16(px0);
            if ((int)(v[0] >> 32) >= 1 && (int)(v[1] >> 32) >= 1) {
                *(float2*)&x_s[2 * tid] =
                    make_float2(__uint_as_float((unsigned)v[0]),
                                __uint_as_float((unsigned)v[1]));
                break;
            }
            __builtin_amdgcn_s_sleep(1);
        }
    }
    __syncthreads();
    if (isZ) {
        const float4* x4 = (const float4*)x_s;
        float acc = 0.f;
#pragma unroll
        for (int k = 0; k < 16; ++k) acc += dot4f(wxr[k], x4[q + 16 * k]);
#pragma unroll
        for (int m = 8; m >= 1; m >>= 1) acc += __shfl_xor(acc, m);
        if (q == 0) zw[rB] = bi + acc;   // h_{-1}=0
    }

    // ---------------- main loop ----------------
    for (int t = 0; t < TSTEPS; ++t) {
        // layer-0 ring back-pressure (lazy; margin 4 slots vs RING=64)
        if (lay == 0 && tid == 0 && t - 60 > l2c) {
            for (;;) {
                unsigned long long v = ld8(prog);
                if ((int)(v >> 32) >= t - 60) { l2c = (int)(v >> 32); break; }
                __builtin_amdgcn_s_sleep(1);
            }
        }

        // ---- stage r_{t-1}: 16B per thread from own replica, tags >= t ----
        if (tid < RTOT / 2) {
            const unsigned long long* pr = &rrep[rep * RTOT + 2 * tid];
            for (;;) {
                ull2 v = ld16(pr);
                if ((int)(v[0] >> 32) >= t && (int)(v[1] >> 32) >= t) {
                    *(float2*)&r_s[2 * tid] =
                        make_float2(__uint_as_float((unsigned)v[0]),
                                    __uint_as_float((unsigned)v[1]));
                    break;
                }
                __builtin_amdgcn_s_sleep(1);
            }
        }
        __syncthreads();

        // ---- phase A: h_t = tanh(zw + V1 r1 + V2 r2); paired publication ----
        {
            const float4* r1v = (const float4*)r_s;
            const float4* r2v = (const float4*)(r_s + DR1);
            float acc = dot4f(wa[0], r1v[p]);
            acc += dot4f(wa[1], r1v[p + 32]);
            acc += dot4f(wa[2], r1v[p + 64]);
            acc += dot4f(wa[3], r1v[p + 96]);
            acc += dot4f(wa[4], r2v[p]);
            acc += dot4f(wa[5], r2v[p + 32]);
#pragma unroll
            for (int m = 16; m >= 1; m >>= 1) acc += __shfl_xor(acc, m);
            float hv  = tanhf(zw[rA] + acc);     // all lanes (wave-uniform cost)
            float hvp = __shfl_xor(hv, 32);      // partner row's value
            if ((tid & 63) == 0) {               // wave-lane 0: rows rA, rA+1
                unsigned long long e0 = mktag(t + 1, hv);
                unsigned long long e1 = mktag(t + 1, hvp);
#pragma unroll
                for (int k = 0; k < NREP; ++k)
                    st16(&hrep[k * D_HH + iA], e0, e1);
                if (lay == 0) {
                    st16(&ring[(size_t)(t & RMASK) * D_HH + iA], e0, e1);
                } else {
                    *(float2*)&out[(size_t)t * D_HH + iA] = make_float2(hv, hvp);
                    if (iA == 0) st8(prog, t + 1, 0u);
                }
                *(float2*)&h_s[iA] = make_float2(hv, hvp);   // self-stage
            }
        }

        // layer-0: prefetch x_{t+1} into LDS (off critical path)
        if (lay == 0) {
            const int ti = (t + 1 < TSTEPS) ? t + 1 : TSTEPS - 1;
            float2 xv = *(const float2*)&x[(size_t)ti * D_HH + 2 * tid];
            *(float2*)&x_s[2 * tid] = xv;
        }

        // ---- stage h_t (skip own rows); layer-1 also stages x_{t+1} ----
        {
            bool dh = ((tid >> 3) == g);   // own 2-entry chunk: self-staged
            const unsigned long long* ph = &hrep[rep * D_HH + 2 * tid];
            if (lay == 0) {
                if (!dh) {
                    for (;;) {
                        ull2 v = ld16(ph);
                        if ((int)(v[0] >> 32) >= t + 1 && (int)(v[1] >> 32) >= t + 1) {
                            *(float2*)&h_s[2 * tid] =
                                make_float2(__uint_as_float((unsigned)v[0]),
                                            __uint_as_float((unsigned)v[1]));
                            break;
                        }
                        __builtin_amdgcn_s_sleep(1);
                    }
                }
            } else {
                const bool needx = (t + 1 < TSTEPS);
                bool dx = !needx;
                const unsigned long long* px =
                    &ring[(size_t)((t + 1) & RMASK) * D_HH + 2 * tid];
                while (!(dh && dx)) {
                    ull2 a, b;
                    ld16x2(ph, px, a, b);
                    if (!dh && (int)(a[0] >> 32) >= t + 1 && (int)(a[1] >> 32) >= t + 1) {
                        *(float2*)&h_s[2 * tid] =
                            make_float2(__uint_as_float((unsigned)a[0]),
                                        __uint_as_float((unsigned)a[1]));
                        dh = true;
                    }
                    if (!dx && (int)(b[0] >> 32) >= t + 2 && (int)(b[1] >> 32) >= t + 2) {
                        *(float2*)&x_s[2 * tid] =
                            make_float2(__uint_as_float((unsigned)b[0]),
                                        __uint_as_float((unsigned)b[1]));
                        dx = true;
                    }
                    if (!(dh && dx)) __builtin_amdgcn_s_sleep(1);
                }
            }
        }
        __syncthreads();

        // ---- phase B: Q rows -> r_t (paired publication) ; Z rows -> zw_{t+1}
        if (rB < NROWB) {
            const float4* h4 = (const float4*)h_s;
            float acc = 0.f;
#pragma unroll
            for (int k = 0; k < 16; ++k) acc += dot4f(wb[k], h4[q + 16 * k]);
            if (isZ) {
                const float4* x4 = (const float4*)x_s;
#pragma unroll
                for (int k = 0; k < 16; ++k) acc += dot4f(wxr[k], x4[q + 16 * k]);
            }
#pragma unroll
            for (int m = 8; m >= 1; m >>= 1) acc += __shfl_xor(acc, m);
            if (isZ) {
                if (q == 0) zw[rB] = bi + acc;
            } else {
                float accp = __shfl_xor(acc, 16);    // partner Q-row's sum
                if (q == 0 && !(rB & 1)) {           // even Q-row publishes pair
                    rloc0 = 0.9f * rloc0 + 0.1f * tanhf(acc);
                    rloc1 = 0.9f * rloc1 + 0.1f * tanhf(accp);
                    unsigned long long e0 = mktag(t + 1, rloc0);
                    unsigned long long e1 = mktag(t + 1, rloc1);
#pragma unroll
                    for (int k = 0; k < NREP; ++k)
                        st16(&rrep[k * RTOT + jG], e0, e1);
                }
            }
        }
    }
}

extern "C" void kernel_launch(void* const* d_in, const int* in_sizes, int n_in,
                              void* d_out, int out_size, void* d_ws, size_t ws_size,
                              hipStream_t stream)
{
    const float* x  = (const float*)d_in[0];
    const float* Wx = (const float*)d_in[1];
    const float* Wh = (const float*)d_in[2];
    const float* b  = (const float*)d_in[3];
    const float* V1 = (const float*)d_in[4];
    const float* U1 = (const float*)d_in[5];
    const float* V2 = (const float*)d_in[6];
    const float* U2 = (const float*)d_in[7];
    float* out = (float*)d_out;

    unsigned long long* ring  = (unsigned long long*)d_ws;          // RING*D_HH
    unsigned long long* h1rep = ring + (size_t)RING * D_HH;         // NREP*D_HH
    unsigned long long* h2rep = h1rep + NREP * D_HH;                // NREP*D_HH
    unsigned long long* r1rep = h2rep + NREP * D_HH;                // NREP*RTOT
    unsigned long long* r2rep = r1rep + NREP * RTOT;                // NREP*RTOT
    unsigned long long* prog  = r2rep + NREP * RTOT;                // 8 (pad)
    const size_t stateB =
        ((size_t)RING * D_HH + 2 * NREP * D_HH + 2 * NREP * RTOT + 8) *
        sizeof(unsigned long long);

    hipMemsetAsync(d_ws, 0, stateB, stream);
    crsd_fused<<<dim3(2 * NB), dim3(BS), 0, stream>>>(
        x, Wx, Wh, b, V1, U1, V2, U2, out,
        ring, h1rep, h2rep, r1rep, r2rep, prog);
}